// Round 1
// baseline (319.866 us; speedup 1.0000x reference)
//
#include <hip/hip_runtime.h>

// ComplexSuperposition: B=128, T=128, D=512
//   out_r[b,d] = sum_t real[b,t,d] * w[b,t]   (same for imag)
//   output_r[b,i,j] = or[b,i]*or[b,j] + oi[b,i]*oi[b,j]
//   output_i[b,i,j] = oi[b,i]*or[b,j] - or[b,i]*oi[b,j]
// Outputs concatenated flat: [output_r (B*D*D) | output_i (B*D*D)], f32.
// Memory-bound: ~268 MB writes (stage 2) + ~67 MB reads (stage 1).

#define B_  128
#define T_  128
#define D_  512
#define D4_ 128   // D / 4 (float4 columns)

// ---------------- Stage 1: weighted reduction over T ----------------
// grid = B_, block = 512. tid -> (d4 = tid&127, q = tid>>7).
// Each quarter-group accumulates 32 t's; 4-way LDS combine.
__global__ __launch_bounds__(512)
void reduce_kernel(const float4* __restrict__ xr,
                   const float4* __restrict__ xi,
                   const float*  __restrict__ w,
                   float4* __restrict__ outr,
                   float4* __restrict__ outi)
{
    const int b   = blockIdx.x;
    const int tid = threadIdx.x;
    const int d4  = tid & (D4_ - 1);
    const int q   = tid >> 7;          // 0..3

    __shared__ float ws[T_];
    if (tid < T_) ws[tid] = w[b * T_ + tid];
    __syncthreads();

    const float4* br = xr + (size_t)b * T_ * D4_;
    const float4* bi = xi + (size_t)b * T_ * D4_;

    float4 ar = make_float4(0.f, 0.f, 0.f, 0.f);
    float4 ai = make_float4(0.f, 0.f, 0.f, 0.f);

    const int t0 = q * (T_ / 4);
    #pragma unroll 4
    for (int t = t0; t < t0 + T_ / 4; ++t) {
        const float wt = ws[t];
        const float4 r  = br[t * D4_ + d4];
        const float4 im = bi[t * D4_ + d4];
        ar.x += r.x  * wt; ar.y += r.y  * wt; ar.z += r.z  * wt; ar.w += r.w  * wt;
        ai.x += im.x * wt; ai.y += im.y * wt; ai.z += im.z * wt; ai.w += im.w * wt;
    }

    __shared__ __align__(16) float4 pr[3][D4_];
    __shared__ __align__(16) float4 pi[3][D4_];
    if (q > 0) { pr[q - 1][d4] = ar; pi[q - 1][d4] = ai; }
    __syncthreads();

    if (q == 0) {
        #pragma unroll
        for (int k = 0; k < 3; ++k) {
            const float4 r  = pr[k][d4];
            const float4 im = pi[k][d4];
            ar.x += r.x;  ar.y += r.y;  ar.z += r.z;  ar.w += r.w;
            ai.x += im.x; ai.y += im.y; ai.z += im.z; ai.w += im.w;
        }
        outr[b * D4_ + d4] = ar;
        outi[b * D4_ + d4] = ai;
    }
}

// ---------------- Stage 2: per-b outer products ----------------
// grid = (D_/ROWS, B_), block = 256. Each block: one b, ROWS=16 i-rows.
// tid -> (j4 = tid&127, isub = tid>>7): two rows in flight per iteration.
#define ROWS_ 16

__global__ __launch_bounds__(256)
void outer_kernel(const float* __restrict__ our,
                  const float* __restrict__ oui,
                  float4* __restrict__ outR,
                  float4* __restrict__ outI)
{
    const int b     = blockIdx.y;
    const int chunk = blockIdx.x;          // 0 .. D_/ROWS_ - 1
    const int tid   = threadIdx.x;

    __shared__ __align__(16) float sr[D_];
    __shared__ __align__(16) float si[D_];
    for (int k = tid; k < D_; k += 256) {
        sr[k] = our[b * D_ + k];
        si[k] = oui[b * D_ + k];
    }
    __syncthreads();

    const int j4   = tid & (D4_ - 1);
    const int isub = tid >> 7;             // 0..1

    const float4 rj = reinterpret_cast<const float4*>(sr)[j4];
    const float4 ij = reinterpret_cast<const float4*>(si)[j4];

    const size_t base = ((size_t)b * D_ + (size_t)chunk * ROWS_) * D4_;

    #pragma unroll
    for (int r = 0; r < ROWS_; r += 2) {
        const int   i  = chunk * ROWS_ + r + isub;
        const float ri = sr[i];
        const float im = si[i];

        float4 oR, oI;
        oR.x = ri * rj.x + im * ij.x;
        oR.y = ri * rj.y + im * ij.y;
        oR.z = ri * rj.z + im * ij.z;
        oR.w = ri * rj.w + im * ij.w;

        oI.x = im * rj.x - ri * ij.x;
        oI.y = im * rj.y - ri * ij.y;
        oI.z = im * rj.z - ri * ij.z;
        oI.w = im * rj.w - ri * ij.w;

        const size_t off = base + (size_t)(r + isub) * D4_ + j4;
        outR[off] = oR;
        outI[off] = oI;
    }
}

extern "C" void kernel_launch(void* const* d_in, const int* in_sizes, int n_in,
                              void* d_out, int out_size, void* d_ws, size_t ws_size,
                              hipStream_t stream) {
    const float* xr = (const float*)d_in[0];   // (B, T, D) f32
    const float* xi = (const float*)d_in[1];   // (B, T, D) f32
    const float* w  = (const float*)d_in[2];   // (B, T)    f32

    float* out  = (float*)d_out;               // [output_r | output_i]
    float* our  = (float*)d_ws;                // B*D floats
    float* oui  = our + B_ * D_;               // B*D floats (ws needs 512 KB)

    reduce_kernel<<<B_, 512, 0, stream>>>(
        (const float4*)xr, (const float4*)xi, w,
        (float4*)our, (float4*)oui);

    dim3 grid(D_ / ROWS_, B_);
    outer_kernel<<<grid, 256, 0, stream>>>(
        our, oui,
        (float4*)out,
        (float4*)(out + (size_t)B_ * D_ * D_));
}

// Round 3
// 313.271 us; speedup vs baseline: 1.0211x; 1.0211x over previous
//
#include <hip/hip_runtime.h>

// ComplexSuperposition: B=128, T=128, D=512
//   out_r[b,d] = sum_t real[b,t,d] * w[b,t]   (same for imag)
//   output_r[b,i,j] = or[b,i]*or[b,j] + oi[b,i]*oi[b,j]
//   output_i[b,i,j] = oi[b,i]*or[b,j] - or[b,i]*oi[b,j]
// Outputs concatenated flat: [output_r (B*D*D) | output_i (B*D*D)], f32.
// Roofline: stage1 reads 67 MB (~11 us), stage2 writes 268 MB (~43 us).

#define B_  128
#define T_  128
#define D_  512
#define D4_ 128   // D / 4 (float4 columns)

// Native vector type: __builtin_nontemporal_store requires it (HIP float4 is
// a class and is rejected).
typedef float f32x4 __attribute__((ext_vector_type(4)));

// ---------------- Stage 1: weighted reduction over T ----------------
// grid = (4, B_) = 512 blocks, 256 threads.
// tid -> (c = tid&31: float4 col within chunk, g = tid>>5: t-group of 16).
// Weights LDS -> registers BEFORE the loop: hot loop is pure global loads+FMA.
__global__ __launch_bounds__(256)
void reduce_kernel(const f32x4* __restrict__ xr,
                   const f32x4* __restrict__ xi,
                   const float* __restrict__ w,
                   f32x4* __restrict__ outr,
                   f32x4* __restrict__ outi)
{
    const int b     = blockIdx.y;
    const int chunk = blockIdx.x;      // 0..3
    const int tid   = threadIdx.x;
    const int c     = tid & 31;
    const int g     = tid >> 5;        // 0..7
    const int d4    = chunk * 32 + c;

    __shared__ float ws[T_];
    if (tid < T_) ws[tid] = w[b * T_ + tid];
    __syncthreads();

    float wreg[16];
    #pragma unroll
    for (int k = 0; k < 16; ++k) wreg[k] = ws[g * 16 + k];

    const f32x4* br = xr + ((size_t)b * T_ + g * 16) * D4_ + d4;
    const f32x4* bm = xi + ((size_t)b * T_ + g * 16) * D4_ + d4;

    f32x4 ar = (f32x4)0.f;
    f32x4 ai = (f32x4)0.f;

    #pragma unroll
    for (int k = 0; k < 16; ++k) {
        const f32x4 r = br[k * D4_];
        const f32x4 m = bm[k * D4_];
        const float wt = wreg[k];
        ar += r * wt;
        ai += m * wt;
    }

    __shared__ __align__(16) f32x4 pr[8][32];
    __shared__ __align__(16) f32x4 pi[8][32];
    pr[g][c] = ar;
    pi[g][c] = ai;
    __syncthreads();

    if (g == 0) {
        #pragma unroll
        for (int k = 1; k < 8; ++k) {
            ar += pr[k][c];
            ai += pi[k][c];
        }
        outr[b * D4_ + d4] = ar;
        outi[b * D4_ + d4] = ai;
    }
}

// ---------------- Stage 2: per-b outer products ----------------
// grid = (32, B_) = 4096 blocks, 256 threads. Block = one b x 16 i-rows.
// tid -> (j4 = tid&127, isub = tid>>7). Row scalars preloaded to registers;
// hot loop = pure VALU + 16 nontemporal 16B stores.
#define ROWS_ 16

__global__ __launch_bounds__(256)
void outer_kernel(const f32x4* __restrict__ our4,
                  const f32x4* __restrict__ oui4,
                  f32x4* __restrict__ outR,
                  f32x4* __restrict__ outI)
{
    const int b     = blockIdx.y;
    const int chunk = blockIdx.x;          // 0..31
    const int tid   = threadIdx.x;

    __shared__ __align__(16) f32x4 s4r[D4_];
    __shared__ __align__(16) f32x4 s4i[D4_];
    if (tid < 128) s4r[tid]       = our4[b * D4_ + tid];
    else           s4i[tid - 128] = oui4[b * D4_ + (tid - 128)];
    __syncthreads();

    const int j4   = tid & (D4_ - 1);
    const int isub = tid >> 7;             // 0..1

    const f32x4 rj = s4r[j4];
    const f32x4 ij = s4i[j4];
    const float* sr = (const float*)s4r;
    const float* si = (const float*)s4i;

    float ri[ROWS_ / 2], mi[ROWS_ / 2];
    #pragma unroll
    for (int r = 0; r < ROWS_ / 2; ++r) {
        const int i = chunk * ROWS_ + 2 * r + isub;
        ri[r] = sr[i];                     // wave-uniform -> LDS broadcast
        mi[r] = si[i];
    }

    const size_t base = ((size_t)b * D_ + (size_t)chunk * ROWS_) * D4_ + j4;

    #pragma unroll
    for (int r = 0; r < ROWS_ / 2; ++r) {
        const float a = ri[r];
        const float m = mi[r];

        const f32x4 oR = a * rj + m * ij;
        const f32x4 oI = m * rj - a * ij;

        const size_t off = base + (size_t)(2 * r + isub) * D4_;
        __builtin_nontemporal_store(oR, &outR[off]);
        __builtin_nontemporal_store(oI, &outI[off]);
    }
}

extern "C" void kernel_launch(void* const* d_in, const int* in_sizes, int n_in,
                              void* d_out, int out_size, void* d_ws, size_t ws_size,
                              hipStream_t stream) {
    const float* xr = (const float*)d_in[0];   // (B, T, D) f32
    const float* xi = (const float*)d_in[1];   // (B, T, D) f32
    const float* w  = (const float*)d_in[2];   // (B, T)    f32

    float* out = (float*)d_out;                // [output_r | output_i]
    float* our = (float*)d_ws;                 // B*D floats
    float* oui = our + B_ * D_;                // B*D floats

    reduce_kernel<<<dim3(4, B_), 256, 0, stream>>>(
        (const f32x4*)xr, (const f32x4*)xi, w,
        (f32x4*)our, (f32x4*)oui);

    outer_kernel<<<dim3(32, B_), 256, 0, stream>>>(
        (const f32x4*)our, (const f32x4*)oui,
        (f32x4*)out,
        (f32x4*)(out + (size_t)B_ * D_ * D_));
}